// Round 1
// baseline (1437.160 us; speedup 1.0000x reference)
//
#include <hip/hip_runtime.h>

// Problem constants (validated against in_sizes at runtime where cheap)
#define D 64
#define D4 (D / 4)   // 16 float4 per row

__device__ __forceinline__ float elu1(float z) {
    return z > 0.0f ? z : expm1f(z);
}

// Kernel 1: emb[i] = elu(x[i] * w[i % D]) ; also zero-init out (harness poisons it).
// One thread per float4 (n_nodes * 16 threads).
__global__ void emb_zero_kernel(const float* __restrict__ x,
                                const float* __restrict__ w,
                                float* __restrict__ emb,
                                float* __restrict__ out,
                                int total4) {
    int i = blockIdx.x * blockDim.x + threadIdx.x;
    if (i >= total4) return;
    const float4* x4 = (const float4*)x;
    const float4* w4 = (const float4*)w;
    float4 xv = x4[i];
    float4 wv = w4[i & (D4 - 1)];
    float4 r;
    r.x = elu1(xv.x * wv.x);
    r.y = elu1(xv.y * wv.y);
    r.z = elu1(xv.z * wv.z);
    r.w = elu1(xv.w * wv.w);
    ((float4*)emb)[i] = r;
    ((float4*)out)[i] = make_float4(0.f, 0.f, 0.f, 0.f);
}

// Fallback zero kernel (used only if ws too small for emb)
__global__ void zero_kernel(float* __restrict__ out, int total4) {
    int i = blockIdx.x * blockDim.x + threadIdx.x;
    if (i < total4) ((float4*)out)[i] = make_float4(0.f, 0.f, 0.f, 0.f);
}

// Kernel 2: per (edge, float4-column) scatter: out[dst] += emb[src]
// 16 threads per edge; coalesced dwordx4 gather, 4 fp32 HW atomics per thread.
__global__ void scatter_kernel(const float* __restrict__ emb,
                               const int* __restrict__ src,
                               const int* __restrict__ dst,
                               float* __restrict__ out,
                               int n_edges) {
    int t = blockIdx.x * blockDim.x + threadIdx.x;
    int e = t >> 4;
    int c = t & 15;
    if (e >= n_edges) return;
    int s = src[e];
    int d = dst[e];
    float4 v = ((const float4*)emb)[s * D4 + c];
    float* o = out + d * D + c * 4;
    unsafeAtomicAdd(o + 0, v.x);
    unsafeAtomicAdd(o + 1, v.y);
    unsafeAtomicAdd(o + 2, v.z);
    unsafeAtomicAdd(o + 3, v.w);
}

// Fallback: fused ELU inside the scatter (no workspace needed)
__global__ void scatter_fused_kernel(const float* __restrict__ x,
                                     const float* __restrict__ w,
                                     const int* __restrict__ src,
                                     const int* __restrict__ dst,
                                     float* __restrict__ out,
                                     int n_edges) {
    int t = blockIdx.x * blockDim.x + threadIdx.x;
    int e = t >> 4;
    int c = t & 15;
    if (e >= n_edges) return;
    int s = src[e];
    int d = dst[e];
    float4 xv = ((const float4*)x)[s * D4 + c];
    float4 wv = ((const float4*)w)[c];
    float4 v;
    v.x = elu1(xv.x * wv.x);
    v.y = elu1(xv.y * wv.y);
    v.z = elu1(xv.z * wv.z);
    v.w = elu1(xv.w * wv.w);
    float* o = out + d * D + c * 4;
    unsafeAtomicAdd(o + 0, v.x);
    unsafeAtomicAdd(o + 1, v.y);
    unsafeAtomicAdd(o + 2, v.z);
    unsafeAtomicAdd(o + 3, v.w);
}

extern "C" void kernel_launch(void* const* d_in, const int* in_sizes, int n_in,
                              void* d_out, int out_size, void* d_ws, size_t ws_size,
                              hipStream_t stream) {
    const float* x   = (const float*)d_in[0];   // [N, 64] fp32
    const float* w   = (const float*)d_in[1];   // [1, 64] fp32
    const int*   src = (const int*)d_in[2];     // [E] int32
    const int*   dst = (const int*)d_in[3];     // [E] int32
    float* out = (float*)d_out;

    const int n_nodes = in_sizes[0] / D;
    const int n_edges = in_sizes[2];
    const int total4  = n_nodes * D4;           // float4 count of [N, 64]

    const size_t emb_bytes = (size_t)n_nodes * D * sizeof(float);
    const int block = 256;

    if (ws_size >= emb_bytes) {
        float* emb = (float*)d_ws;
        emb_zero_kernel<<<(total4 + block - 1) / block, block, 0, stream>>>(
            x, w, emb, out, total4);
        const int nt = n_edges * 16;
        scatter_kernel<<<(nt + block - 1) / block, block, 0, stream>>>(
            emb, src, dst, out, n_edges);
    } else {
        zero_kernel<<<(total4 + block - 1) / block, block, 0, stream>>>(out, total4);
        const int nt = n_edges * 16;
        scatter_fused_kernel<<<(nt + block - 1) / block, block, 0, stream>>>(
            x, w, src, dst, out, n_edges);
    }
}

// Round 2
// 419.840 us; speedup vs baseline: 3.4231x; 3.4231x over previous
//
#include <hip/hip_runtime.h>

#define D 64
#define D4 (D / 4)   // 16 float4 per row

__device__ __forceinline__ float elu1(float z) {
    return z > 0.0f ? z : expm1f(z);
}

// ---------- Sorted (counting-sort) pipeline ----------

// K1: emb[i] = elu(x[i]*w[i%D]); also zero counts[] (hist runs after us on stream).
__global__ void emb_zero_counts_kernel(const float* __restrict__ x,
                                       const float* __restrict__ w,
                                       float* __restrict__ emb,
                                       int* __restrict__ counts,
                                       int total4, int n_nodes) {
    int i = blockIdx.x * blockDim.x + threadIdx.x;
    if (i < n_nodes) counts[i] = 0;
    if (i >= total4) return;
    float4 xv = ((const float4*)x)[i];
    float4 wv = ((const float4*)w)[i & (D4 - 1)];
    float4 r;
    r.x = elu1(xv.x * wv.x);
    r.y = elu1(xv.y * wv.y);
    r.z = elu1(xv.z * wv.z);
    r.w = elu1(xv.w * wv.w);
    ((float4*)emb)[i] = r;
}

// K1b (no-emb tier): just zero counts.
__global__ void zero_counts_kernel(int* __restrict__ counts, int n_nodes) {
    int i = blockIdx.x * blockDim.x + threadIdx.x;
    if (i < n_nodes) counts[i] = 0;
}

// K2: histogram of dst.
__global__ void hist_kernel(const int* __restrict__ dst,
                            int* __restrict__ counts, int n_edges) {
    int i = blockIdx.x * blockDim.x + threadIdx.x;
    if (i < n_edges) atomicAdd(&counts[dst[i]], 1);
}

// K3: single-block exclusive scan of counts[0..n) -> offsets[0..n], cursor copy.
__global__ void scan_kernel(const int* __restrict__ counts,
                            int* __restrict__ offsets,
                            int* __restrict__ cursor, int n) {
    __shared__ int smem[17];            // 16 wave sums + block total
    const int tid = threadIdx.x;        // 1024 threads = 16 waves
    const int lane = tid & 63, wid = tid >> 6;
    int running = 0;
    for (int base = 0; base < n; base += 1024) {
        int i = base + tid;
        int v = (i < n) ? counts[i] : 0;
        int incl = v;
        #pragma unroll
        for (int off = 1; off < 64; off <<= 1) {
            int t = __shfl_up(incl, off, 64);
            if (lane >= off) incl += t;
        }
        if (lane == 63) smem[wid] = incl;
        __syncthreads();
        if (tid < 16) {
            int ws = smem[tid];
            int wincl = ws;
            #pragma unroll
            for (int off = 1; off < 16; off <<= 1) {
                int t = __shfl_up(wincl, off, 16);
                if (tid >= off) wincl += t;
            }
            smem[tid] = wincl - ws;          // exclusive wave offset
            if (tid == 15) smem[16] = wincl; // block total
        }
        __syncthreads();
        int excl = running + smem[wid] + (incl - v);
        if (i < n) { offsets[i] = excl; cursor[i] = excl; }
        running += smem[16];
        __syncthreads();                     // smem reused next tile
    }
    if (tid == 0) offsets[n] = running;
}

// K4: bin edges by dst.
__global__ void bin_kernel(const int* __restrict__ src,
                           const int* __restrict__ dst,
                           int* __restrict__ cursor,
                           int* __restrict__ sorted_src, int n_edges) {
    int i = blockIdx.x * blockDim.x + threadIdx.x;
    if (i < n_edges) {
        int pos = atomicAdd(&cursor[dst[i]], 1);
        sorted_src[pos] = src[i];
    }
}

// K5: one wave per node. Lane layout: g = lane>>4 picks one of 4 edges per
// iteration, c = lane&15 picks the float4 column. Shuffle-reduce across the
// 4 groups, group 0 writes the row (non-atomic, coalesced 256B).
__global__ void gather_sum_kernel(const float* __restrict__ emb,
                                  const int* __restrict__ sorted_src,
                                  const int* __restrict__ offsets,
                                  float* __restrict__ out, int n_nodes) {
    int wave = (blockIdx.x * blockDim.x + threadIdx.x) >> 6;
    if (wave >= n_nodes) return;
    int lane = threadIdx.x & 63;
    int g = lane >> 4;
    int c = lane & 15;
    int beg = offsets[wave], end = offsets[wave + 1];
    float4 acc = make_float4(0.f, 0.f, 0.f, 0.f);
    for (int e = beg + g; e < end; e += 4) {
        int s = sorted_src[e];
        float4 v = ((const float4*)emb)[s * D4 + c];
        acc.x += v.x; acc.y += v.y; acc.z += v.z; acc.w += v.w;
    }
    #pragma unroll
    for (int off = 16; off <= 32; off <<= 1) {
        acc.x += __shfl_xor(acc.x, off, 64);
        acc.y += __shfl_xor(acc.y, off, 64);
        acc.z += __shfl_xor(acc.z, off, 64);
        acc.w += __shfl_xor(acc.w, off, 64);
    }
    if (g == 0) ((float4*)out)[wave * D4 + c] = acc;
}

// K5b (no-emb tier): elu(x*w) computed on the fly per edge.
__global__ void gather_sum_fused_kernel(const float* __restrict__ x,
                                        const float* __restrict__ w,
                                        const int* __restrict__ sorted_src,
                                        const int* __restrict__ offsets,
                                        float* __restrict__ out, int n_nodes) {
    int wave = (blockIdx.x * blockDim.x + threadIdx.x) >> 6;
    if (wave >= n_nodes) return;
    int lane = threadIdx.x & 63;
    int g = lane >> 4;
    int c = lane & 15;
    float4 wv = ((const float4*)w)[c];
    int beg = offsets[wave], end = offsets[wave + 1];
    float4 acc = make_float4(0.f, 0.f, 0.f, 0.f);
    for (int e = beg + g; e < end; e += 4) {
        int s = sorted_src[e];
        float4 xv = ((const float4*)x)[s * D4 + c];
        acc.x += elu1(xv.x * wv.x);
        acc.y += elu1(xv.y * wv.y);
        acc.z += elu1(xv.z * wv.z);
        acc.w += elu1(xv.w * wv.w);
    }
    #pragma unroll
    for (int off = 16; off <= 32; off <<= 1) {
        acc.x += __shfl_xor(acc.x, off, 64);
        acc.y += __shfl_xor(acc.y, off, 64);
        acc.z += __shfl_xor(acc.z, off, 64);
        acc.w += __shfl_xor(acc.w, off, 64);
    }
    if (g == 0) ((float4*)out)[wave * D4 + c] = acc;
}

// ---------- Fallback: atomic scatter (round-1 path) ----------
__global__ void zero_out_kernel(float* __restrict__ out, int total4) {
    int i = blockIdx.x * blockDim.x + threadIdx.x;
    if (i < total4) ((float4*)out)[i] = make_float4(0.f, 0.f, 0.f, 0.f);
}

__global__ void scatter_fused_kernel(const float* __restrict__ x,
                                     const float* __restrict__ w,
                                     const int* __restrict__ src,
                                     const int* __restrict__ dst,
                                     float* __restrict__ out, int n_edges) {
    int t = blockIdx.x * blockDim.x + threadIdx.x;
    int e = t >> 4;
    int c = t & 15;
    if (e >= n_edges) return;
    int s = src[e];
    int d = dst[e];
    float4 xv = ((const float4*)x)[s * D4 + c];
    float4 wv = ((const float4*)w)[c];
    float* o = out + d * D + c * 4;
    unsafeAtomicAdd(o + 0, elu1(xv.x * wv.x));
    unsafeAtomicAdd(o + 1, elu1(xv.y * wv.y));
    unsafeAtomicAdd(o + 2, elu1(xv.z * wv.z));
    unsafeAtomicAdd(o + 3, elu1(xv.w * wv.w));
}

extern "C" void kernel_launch(void* const* d_in, const int* in_sizes, int n_in,
                              void* d_out, int out_size, void* d_ws, size_t ws_size,
                              hipStream_t stream) {
    const float* x   = (const float*)d_in[0];   // [N, 64] fp32
    const float* w   = (const float*)d_in[1];   // [1, 64] fp32
    const int*   src = (const int*)d_in[2];     // [E] int32
    const int*   dst = (const int*)d_in[3];     // [E] int32
    float* out = (float*)d_out;

    const int n_nodes = in_sizes[0] / D;
    const int n_edges = in_sizes[2];
    const int total4  = n_nodes * D4;
    const int block = 256;

    // Workspace layout (16B-aligned slices)
    auto align16 = [](size_t v) { return (v + 15) & ~size_t(15); };
    const size_t emb_b     = align16((size_t)n_nodes * D * sizeof(float));
    const size_t offsets_b = align16((size_t)(n_nodes + 1) * sizeof(int));
    const size_t cursor_b  = align16((size_t)n_nodes * sizeof(int));
    const size_t sorted_b  = align16((size_t)n_edges * sizeof(int));
    const size_t need_full = emb_b + offsets_b + cursor_b + sorted_b;
    const size_t need_lite = offsets_b + cursor_b + sorted_b;

    const int edge_blocks = (n_edges + block - 1) / block;
    const int node_blocks = (n_nodes + block - 1) / block;
    const int wave_blocks = (n_nodes * 64 + block - 1) / block;  // 1 wave/node

    if (ws_size >= need_full) {
        char* p = (char*)d_ws;
        float* emb     = (float*)p;            p += emb_b;
        int*   offsets = (int*)p;              p += offsets_b;
        int*   cursor  = (int*)p;              p += cursor_b;
        int*   sorted  = (int*)p;
        int*   counts  = cursor;               // counts reuses cursor slot pre-scan? NO:
        // counts must survive until scan reads it; cursor written by scan.
        // Use sorted[] as counts scratch instead (only needed before bin).
        counts = sorted;  // n_edges >= n_nodes here (1.6M >= 100K)

        emb_zero_counts_kernel<<<(total4 + block - 1) / block, block, 0, stream>>>(
            x, w, emb, counts, total4, n_nodes);
        hist_kernel<<<edge_blocks, block, 0, stream>>>(dst, counts, n_edges);
        scan_kernel<<<1, 1024, 0, stream>>>(counts, offsets, cursor, n_nodes);
        bin_kernel<<<edge_blocks, block, 0, stream>>>(src, dst, cursor, sorted, n_edges);
        gather_sum_kernel<<<wave_blocks, block, 0, stream>>>(
            emb, sorted, offsets, out, n_nodes);
    } else if (ws_size >= need_lite && n_edges >= n_nodes) {
        char* p = (char*)d_ws;
        int* offsets = (int*)p;  p += offsets_b;
        int* cursor  = (int*)p;  p += cursor_b;
        int* sorted  = (int*)p;
        int* counts  = sorted;

        zero_counts_kernel<<<node_blocks, block, 0, stream>>>(counts, n_nodes);
        hist_kernel<<<edge_blocks, block, 0, stream>>>(dst, counts, n_edges);
        scan_kernel<<<1, 1024, 0, stream>>>(counts, offsets, cursor, n_nodes);
        bin_kernel<<<edge_blocks, block, 0, stream>>>(src, dst, cursor, sorted, n_edges);
        gather_sum_fused_kernel<<<wave_blocks, block, 0, stream>>>(
            x, w, sorted, offsets, out, n_nodes);
    } else {
        zero_out_kernel<<<(total4 + block - 1) / block, block, 0, stream>>>(out, total4);
        const int nt = n_edges * 16;
        scatter_fused_kernel<<<(nt + block - 1) / block, block, 0, stream>>>(
            x, w, src, dst, out, n_edges);
    }
}

// Round 3
// 294.199 us; speedup vs baseline: 4.8850x; 1.4271x over previous
//
#include <hip/hip_runtime.h>

#define D 64
#define D4 (D / 4)   // 16 float4 per row
#define NPART 8      // XCD count heuristic: blockIdx%8 ~ XCD id (speed-only)

__device__ __forceinline__ float elu1(float z) {
    return z > 0.0f ? z : expm1f(z);
}

// ---------- K1: emb = elu(x*w), zero counts ----------
__global__ void emb_zero_counts_kernel(const float* __restrict__ x,
                                       const float* __restrict__ w,
                                       float* __restrict__ emb,
                                       int* __restrict__ counts,
                                       int total4, int n_nodes) {
    int i = blockIdx.x * blockDim.x + threadIdx.x;
    if (i < n_nodes) counts[i] = 0;
    if (i >= total4) return;
    float4 xv = ((const float4*)x)[i];
    float4 wv = ((const float4*)w)[i & (D4 - 1)];
    float4 r;
    r.x = elu1(xv.x * wv.x);
    r.y = elu1(xv.y * wv.y);
    r.z = elu1(xv.z * wv.z);
    r.w = elu1(xv.w * wv.w);
    ((float4*)emb)[i] = r;
}

// ---------- K2: XCD-partitioned histogram ----------
// Each partition p handles dst in [lo,hi); its count slice stays in one XCD L2.
__global__ void hist_part_kernel(const int* __restrict__ dst,
                                 int* __restrict__ counts,
                                 int n_edges, int n_nodes, int blocks_per_part) {
    int p = blockIdx.x & (NPART - 1);
    int q = blockIdx.x >> 3;
    int lo = (int)(((long long)n_nodes * p) / NPART);
    int hi = (int)(((long long)n_nodes * (p + 1)) / NPART);
    int stride = blocks_per_part * blockDim.x;
    for (int i = q * blockDim.x + threadIdx.x; i < n_edges; i += stride) {
        int d = dst[i];
        if (d >= lo && d < hi) atomicAdd(&counts[d], 1);
    }
}

// ---------- K3a/b/c: multi-block exclusive scan of counts[0..n) ----------
// Phase A: per-1024-tile sums.
__global__ void scan_partials_kernel(const int* __restrict__ counts,
                                     int* __restrict__ bsum, int n) {
    __shared__ int ws[4];
    int b = blockIdx.x, tid = threadIdx.x;
    int base = b * 1024 + tid * 4;
    int s = 0;
    if (base + 3 < n) {
        int4 v = *(const int4*)(counts + base);
        s = v.x + v.y + v.z + v.w;
    } else {
        for (int k = 0; k < 4; k++) if (base + k < n) s += counts[base + k];
    }
    #pragma unroll
    for (int off = 1; off < 64; off <<= 1) s += __shfl_xor(s, off, 64);
    if ((tid & 63) == 0) ws[tid >> 6] = s;
    __syncthreads();
    if (tid == 0) bsum[b] = ws[0] + ws[1] + ws[2] + ws[3];
}

// Phase B: single small block scans the tile sums (nb ~ 98), writes total.
__global__ void scan_bsums_kernel(const int* __restrict__ bsum,
                                  int* __restrict__ boff,
                                  int* __restrict__ total_out, int nb) {
    __shared__ int wtot[2];
    __shared__ int running_s;
    int tid = threadIdx.x;  // 128 threads
    if (tid == 0) running_s = 0;
    __syncthreads();
    for (int base = 0; base < nb; base += 128) {
        int i = base + tid;
        int v = (i < nb) ? bsum[i] : 0;
        int incl = v;
        #pragma unroll
        for (int off = 1; off < 64; off <<= 1) {
            int t = __shfl_up(incl, off, 64);
            if ((tid & 63) >= off) incl += t;
        }
        if ((tid & 63) == 63) wtot[tid >> 6] = incl;
        __syncthreads();
        int add = (tid >= 64) ? wtot[0] : 0;
        int excl = running_s + add + incl - v;
        if (i < nb) boff[i] = excl;
        __syncthreads();
        if (tid == 0) running_s += wtot[0] + wtot[1];
        __syncthreads();
    }
    if (tid == 0) *total_out = running_s;
}

// Phase C: re-scan each tile, add tile offset, emit offsets + cursor.
__global__ void scan_apply_kernel(const int* __restrict__ counts,
                                  const int* __restrict__ boff,
                                  int* __restrict__ offsets,
                                  int* __restrict__ cursor, int n) {
    __shared__ int wsum[4];
    int b = blockIdx.x, tid = threadIdx.x, lane = tid & 63, wid = tid >> 6;
    int base = b * 1024 + tid * 4;
    int v[4] = {0, 0, 0, 0};
    if (base + 3 < n) {
        int4 t = *(const int4*)(counts + base);
        v[0] = t.x; v[1] = t.y; v[2] = t.z; v[3] = t.w;
    } else {
        for (int k = 0; k < 4; k++) if (base + k < n) v[k] = counts[base + k];
    }
    int tsum = v[0] + v[1] + v[2] + v[3];
    int incl = tsum;
    #pragma unroll
    for (int off = 1; off < 64; off <<= 1) {
        int t = __shfl_up(incl, off, 64);
        if (lane >= off) incl += t;
    }
    if (lane == 63) wsum[wid] = incl;
    __syncthreads();
    int wadd = 0;
    #pragma unroll
    for (int k = 0; k < 4; k++) if (k < wid) wadd += wsum[k];
    int run = boff[b] + wadd + (incl - tsum);
    for (int k = 0; k < 4; k++) {
        if (base + k < n) { offsets[base + k] = run; cursor[base + k] = run; }
        run += v[k];
    }
}

// ---------- K4: XCD-partitioned binning ----------
// Partition p writes only sorted[offsets[lo]..offsets[hi]) (~0.8 MB, L2-local).
__global__ void bin_part_kernel(const int* __restrict__ src,
                                const int* __restrict__ dst,
                                int* __restrict__ cursor,
                                int* __restrict__ sorted_src,
                                int n_edges, int n_nodes, int blocks_per_part) {
    int p = blockIdx.x & (NPART - 1);
    int q = blockIdx.x >> 3;
    int lo = (int)(((long long)n_nodes * p) / NPART);
    int hi = (int)(((long long)n_nodes * (p + 1)) / NPART);
    int stride = blocks_per_part * blockDim.x;
    for (int i = q * blockDim.x + threadIdx.x; i < n_edges; i += stride) {
        int d = dst[i];
        if (d >= lo && d < hi) {
            int pos = atomicAdd(&cursor[d], 1);
            sorted_src[pos] = src[i];
        }
    }
}

// ---------- K5: one wave per node, segment gather-sum ----------
__global__ void gather_sum_kernel(const float* __restrict__ emb,
                                  const int* __restrict__ sorted_src,
                                  const int* __restrict__ offsets,
                                  float* __restrict__ out, int n_nodes) {
    int wave = (blockIdx.x * blockDim.x + threadIdx.x) >> 6;
    if (wave >= n_nodes) return;
    int lane = threadIdx.x & 63;
    int g = lane >> 4;
    int c = lane & 15;
    int beg = offsets[wave], end = offsets[wave + 1];
    float4 acc = make_float4(0.f, 0.f, 0.f, 0.f);
    for (int e = beg + g; e < end; e += 4) {
        int s = sorted_src[e];
        float4 v = ((const float4*)emb)[s * D4 + c];
        acc.x += v.x; acc.y += v.y; acc.z += v.z; acc.w += v.w;
    }
    #pragma unroll
    for (int off = 16; off <= 32; off <<= 1) {
        acc.x += __shfl_xor(acc.x, off, 64);
        acc.y += __shfl_xor(acc.y, off, 64);
        acc.z += __shfl_xor(acc.z, off, 64);
        acc.w += __shfl_xor(acc.w, off, 64);
    }
    if (g == 0) ((float4*)out)[wave * D4 + c] = acc;
}

// ---------- Fallback: atomic scatter (ws too small) ----------
__global__ void zero_out_kernel(float* __restrict__ out, int total4) {
    int i = blockIdx.x * blockDim.x + threadIdx.x;
    if (i < total4) ((float4*)out)[i] = make_float4(0.f, 0.f, 0.f, 0.f);
}

__global__ void scatter_fused_kernel(const float* __restrict__ x,
                                     const float* __restrict__ w,
                                     const int* __restrict__ src,
                                     const int* __restrict__ dst,
                                     float* __restrict__ out, int n_edges) {
    int t = blockIdx.x * blockDim.x + threadIdx.x;
    int e = t >> 4;
    int c = t & 15;
    if (e >= n_edges) return;
    int s = src[e];
    int d = dst[e];
    float4 xv = ((const float4*)x)[s * D4 + c];
    float4 wv = ((const float4*)w)[c];
    float* o = out + d * D + c * 4;
    unsafeAtomicAdd(o + 0, elu1(xv.x * wv.x));
    unsafeAtomicAdd(o + 1, elu1(xv.y * wv.y));
    unsafeAtomicAdd(o + 2, elu1(xv.z * wv.z));
    unsafeAtomicAdd(o + 3, elu1(xv.w * wv.w));
}

extern "C" void kernel_launch(void* const* d_in, const int* in_sizes, int n_in,
                              void* d_out, int out_size, void* d_ws, size_t ws_size,
                              hipStream_t stream) {
    const float* x   = (const float*)d_in[0];   // [N, 64] fp32
    const float* w   = (const float*)d_in[1];   // [1, 64] fp32
    const int*   src = (const int*)d_in[2];     // [E] int32
    const int*   dst = (const int*)d_in[3];     // [E] int32
    float* out = (float*)d_out;

    const int n_nodes = in_sizes[0] / D;
    const int n_edges = in_sizes[2];
    const int total4  = n_nodes * D4;
    const int block = 256;

    auto align16 = [](size_t v) { return (v + 15) & ~size_t(15); };
    const int  nb        = (n_nodes + 1023) / 1024;            // scan tiles
    const size_t emb_b     = align16((size_t)n_nodes * D * sizeof(float));
    const size_t offsets_b = align16((size_t)(n_nodes + 1) * sizeof(int));
    const size_t cursor_b  = align16((size_t)n_nodes * sizeof(int));
    const size_t sorted_b  = align16((size_t)n_edges * sizeof(int));
    const size_t bsum_b    = align16((size_t)nb * sizeof(int));
    const size_t boff_b    = align16((size_t)nb * sizeof(int));
    const size_t need_full = emb_b + offsets_b + cursor_b + sorted_b + bsum_b + boff_b;

    if (ws_size >= need_full && n_edges >= n_nodes) {
        char* p = (char*)d_ws;
        float* emb     = (float*)p;  p += emb_b;
        int*   offsets = (int*)p;    p += offsets_b;
        int*   cursor  = (int*)p;    p += cursor_b;
        int*   sorted  = (int*)p;    p += sorted_b;
        int*   bsum    = (int*)p;    p += bsum_b;
        int*   boff    = (int*)p;
        int*   counts  = sorted;     // counts only needed pre-bin; sorted written post-scan

        const int blocks_per_part = 96;   // 768 blocks total, ~3/CU

        emb_zero_counts_kernel<<<(total4 + block - 1) / block, block, 0, stream>>>(
            x, w, emb, counts, total4, n_nodes);
        hist_part_kernel<<<NPART * blocks_per_part, block, 0, stream>>>(
            dst, counts, n_edges, n_nodes, blocks_per_part);
        scan_partials_kernel<<<nb, 256, 0, stream>>>(counts, bsum, n_nodes);
        scan_bsums_kernel<<<1, 128, 0, stream>>>(bsum, boff, offsets + n_nodes, nb);
        scan_apply_kernel<<<nb, 256, 0, stream>>>(counts, boff, offsets, cursor, n_nodes);
        bin_part_kernel<<<NPART * blocks_per_part, block, 0, stream>>>(
            src, dst, cursor, sorted, n_edges, n_nodes, blocks_per_part);
        const int wave_blocks = (n_nodes * 64 + block - 1) / block;
        gather_sum_kernel<<<wave_blocks, block, 0, stream>>>(
            emb, sorted, offsets, out, n_nodes);
    } else {
        zero_out_kernel<<<(total4 + block - 1) / block, block, 0, stream>>>(out, total4);
        const int nt = n_edges * 16;
        scatter_fused_kernel<<<(nt + block - 1) / block, block, 0, stream>>>(
            x, w, src, dst, out, n_edges);
    }
}